// Round 10
// baseline (31.388 us; speedup 1.0000x reference)
//
#include <hip/hip_runtime.h>
#include <hip/hip_bf16.h>

#define R      1000
#define K      80
#define KP1    81
#define CAND   100
#define NC     (K*CAND)
#define VCAP   256
#define SCORE_THRESH 0.05f
#define NMS_THRESH   0.5f

typedef unsigned long long u64;

// Monotone device globals (module-load zero-init; NOT in d_ws so the harness
// 0xAA poison can't touch them). Each launch: g_flags[k] += 1 (by class k's
// block), g_cons += 1 (by consumer). Invariant at launch L: consumer's
// fetch_add returns L-1 -> N = L; every flag reaches L when its class is done.
__device__ unsigned g_flags[K];
__device__ unsigned g_cons = 0;

__device__ __forceinline__ unsigned int ordf(float f) {
    unsigned int u = __float_as_uint(f);
    return (u & 0x80000000u) ? ~u : (u | 0x80000000u);
}
__device__ __forceinline__ float unordf(unsigned int o) {
    unsigned int u = (o & 0x80000000u) ? (o ^ 0x80000000u) : ~o;
    return __uint_as_float(u);
}

// Agent-scope coherent access (proven R7-R9)
__device__ __forceinline__ void st_agent_u64(u64* p, u64 v) {
    __hip_atomic_store(p, v, __ATOMIC_RELAXED, __HIP_MEMORY_SCOPE_AGENT);
}
__device__ __forceinline__ u64 ld_agent_u64(const u64* p) {
    return __hip_atomic_load(p, __ATOMIC_RELAXED, __HIP_MEMORY_SCOPE_AGENT);
}
__device__ __forceinline__ void st_box(float4* p, float4 b) {
    union { float f[2]; u64 u; } lo, hi;
    lo.f[0] = b.x; lo.f[1] = b.y; hi.f[0] = b.z; hi.f[1] = b.w;
    st_agent_u64((u64*)p, lo.u);
    st_agent_u64((u64*)p + 1, hi.u);
}
__device__ __forceinline__ float4 ld_box(const float4* p) {
    union { float f[2]; u64 u; } lo, hi;
    lo.u = ld_agent_u64((const u64*)p);
    hi.u = ld_agent_u64((const u64*)p + 1);
    return make_float4(lo.f[0], lo.f[1], hi.f[0], hi.f[1]);
}

// ---------------------------------------------------------------------------
// Ballot-matrix build (proven R6-R9)
// ---------------------------------------------------------------------------
template<int NR>
__device__ __forceinline__ void build_matrix(
    int lane, int w, int V, const float4* sboxs, u64* mat)
{
    float4 bx[NR]; float area[NR];
    #pragma unroll
    for (int r = 0; r < NR; ++r) {
        float4 bb = sboxs[r * 64 + lane];
        bx[r] = bb;
        area[r] = (bb.z - bb.x) * (bb.w - bb.y);
    }
    const int Vq = (V + 3) >> 2;
    int jbeg = w * Vq;
    int jend = jbeg + Vq; if (jend > V) jend = V;
    #pragma unroll 2
    for (int j = jbeg; j < jend; ++j) {
        float4 bj = sboxs[j];
        float areaB = (bj.z - bj.x) * (bj.w - bj.y);
        #pragma unroll
        for (int r = 0; r < NR; ++r) {
            float ltx = fmaxf(bx[r].x, bj.x), lty = fmaxf(bx[r].y, bj.y);
            float rbx = fminf(bx[r].z, bj.z), rby = fminf(bx[r].w, bj.w);
            float ww = fmaxf(rbx - ltx, 0.f), hh = fmaxf(rby - lty, 0.f);
            float inter = ww * hh;
            float uni = area[r] + areaB - inter;
            float iou = inter / fmaxf(uni, 1e-9f);   // bit-identical to ref
            mat[j * NR + r] = __ballot(iou > NMS_THRESH);
        }
    }
}

// ---------------------------------------------------------------------------
// Greedy scan (wave 0 only) + candidate emit (proven R6-R9)
// ---------------------------------------------------------------------------
template<int NR>
__device__ __forceinline__ void scan_emit(
    int k, int lane, int V,
    const float4* sboxs, const float* sscs, const u64* mat,
    u64* __restrict__ cand_key, float4* __restrict__ cand_box)
{
    const u64 lt_mask = (1ull << lane) - 1ull;

    u64 kept[NR];
    #pragma unroll
    for (int r = 0; r < NR; ++r) kept[r] = 0ull;
    u64 cur[NR];
    #pragma unroll
    for (int r = 0; r < NR; ++r) cur[r] = mat[r];

    int j = 0;
    #pragma unroll
    for (int jc = 0; jc < NR; ++jc) {
        int jmax = V - jc * 64;
        if (jmax > 64) jmax = 64;
        for (int jl = 0; jl < jmax; ++jl, ++j) {
            u64 nxt[NR];
            #pragma unroll
            for (int r = 0; r < NR; ++r) nxt[r] = mat[(j + 1) * NR + r];
            u64 hit = 0ull;
            #pragma unroll
            for (int r = 0; r < NR; ++r) hit |= cur[r] & kept[r];
            if (hit == 0ull) kept[jc] |= (1ull << jl);
            #pragma unroll
            for (int r = 0; r < NR; ++r) cur[r] = nxt[r];
        }
    }

    unsigned pre = 0;
    u64* ck = cand_key + (size_t)k * CAND;
    float4* cb = cand_box + (size_t)k * CAND;
    #pragma unroll
    for (int r = 0; r < NR; ++r) {
        u64 m = kept[r];
        bool mine = (m >> lane) & 1ull;
        unsigned rank = pre + (unsigned)__popcll(m & lt_mask);
        if (mine && rank < CAND) {
            unsigned c = (unsigned)(k * CAND + rank);
            float s = sscs[r * 64 + lane];
            st_agent_u64(&ck[rank], ((u64)ordf(s) << 32) | (u64)(0xFFFFFFFFu - c));
            st_box(&cb[rank], sboxs[r * 64 + lane]);
        }
        pre += (unsigned)__popcll(m);
    }
    unsigned T100 = pre < CAND ? pre : CAND;
    for (unsigned s2 = T100 + (unsigned)lane; s2 < CAND; s2 += 64)
        st_agent_u64(&ck[s2], 0ull);
}

// ---------------------------------------------------------------------------
// Grid = K+1 blocks x 256.
//  Blocks 0..79 (producers): gather -> rank-sort -> matrix -> scan -> emit ->
//    vmcnt drain -> flag++ (relaxed agent). No trailing barrier, no fences.
//  Block 80 (consumer): spins per class; loads each ready class's 100 keys
//    into registers + histograms them (overlapped with producers). After all
//    80 flags: suffix-scan -> register extraction -> exact rank -> output.
// ---------------------------------------------------------------------------
__global__ __launch_bounds__(256, 1) void fused_kernel(
    const float* __restrict__ boxes, const float* __restrict__ scores,
    const int* __restrict__ imh, const int* __restrict__ imw,
    u64* __restrict__ cand_key, float4* __restrict__ cand_box,
    float* __restrict__ out)
{
    const int tid = threadIdx.x;
    const int lane = tid & 63, w = tid >> 6;

    __shared__ u64    skey[VCAP];
    __shared__ float4 sbox[VCAP];     // compacted order
    __shared__ float4 sboxs[VCAP];    // sorted order
    __shared__ float  sscs[VCAP];     // sorted scores
    __shared__ u64    mat[(VCAP + 1) * 4];
    __shared__ unsigned cnt16[16];
    __shared__ unsigned h768[768];
    __shared__ unsigned hist[4][264];
    __shared__ unsigned wsum[4];
    __shared__ u64 Psh;
    __shared__ unsigned remsh, cntsh, nExtsh, Bsh, Nsh;
    __shared__ int donesh;
    __shared__ u64 Wl[256];

    if (blockIdx.x == K) {
        // ================= consumer block =================
        if (tid == 0) {
            unsigned old = __hip_atomic_fetch_add(&g_cons, 1u, __ATOMIC_RELAXED, __HIP_MEMORY_SCOPE_AGENT);
            Nsh = old + 1u;
            cntsh = 0;
        }
        #pragma unroll
        for (int x = 0; x < 3; ++x) h768[x * 256 + tid] = 0;
        __syncthreads();
        const unsigned N = Nsh;

        // wave w owns classes [20w, 20w+20); keys stashed in registers
        u64 ka[20], kb[20];
        #pragma unroll
        for (int i = 0; i < 20; ++i) {
            const int k2 = w * 20 + i;
            while (__hip_atomic_load(&g_flags[k2], __ATOMIC_RELAXED, __HIP_MEMORY_SCOPE_AGENT) < N)
                __builtin_amdgcn_s_sleep(2);
            asm volatile("" ::: "memory");
            u64 a = ld_agent_u64(&cand_key[(size_t)k2 * CAND + lane]);
            u64 b = (lane < CAND - 64) ? ld_agent_u64(&cand_key[(size_t)k2 * CAND + 64 + lane]) : 0ull;
            ka[i] = a; kb[i] = b;
            if (a) atomicAdd(&h768[(unsigned)(a >> 48) - 0xBD00u], 1u);
            if (b) atomicAdd(&h768[(unsigned)(b >> 48) - 0xBD00u], 1u);
        }
        __syncthreads();

        // suffix-scan (bin-descending) to locate rank-99 threshold bin (R9)
        {
            unsigned h0 = h768[3 * tid], h1 = h768[3 * tid + 1], h2 = h768[3 * tid + 2];
            unsigned local = h0 + h1 + h2;
            unsigned inc = local;
            #pragma unroll
            for (int off = 1; off < 64; off <<= 1) {
                unsigned v = __shfl_down(inc, off);
                if (lane + off < 64) inc += v;
            }
            if (lane == 0) wsum[w] = inc;
            __syncthreads();
            unsigned wafter = 0;
            #pragma unroll
            for (int ww = 0; ww < 4; ++ww) if (ww > w) wafter += wsum[ww];
            unsigned after = inc - local + wafter;

            unsigned G2 = after;
            unsigned G1 = after + h2;
            unsigned G0 = after + h2 + h1;
            if (h2 && G2 <= CAND - 1 && CAND - 1 < G2 + h2) {
                Bsh = 3 * tid + 2; remsh = CAND - 1 - G2; nExtsh = G2 + h2; donesh = 0;
            }
            if (h1 && G1 <= CAND - 1 && CAND - 1 < G1 + h1) {
                Bsh = 3 * tid + 1; remsh = CAND - 1 - G1; nExtsh = G1 + h1; donesh = 0;
            }
            if (h0 && G0 <= CAND - 1 && CAND - 1 < G0 + h0) {
                Bsh = 3 * tid;     remsh = CAND - 1 - G0; nExtsh = G0 + h0; donesh = 0;
            }
            __syncthreads();
        }

        const unsigned B16 = Bsh + 0xBD00u;

        if (nExtsh <= 256) {
            // common case: extract from register stash, exact rank-select
            #pragma unroll
            for (int i = 0; i < 20; ++i) {
                u64 a = ka[i], b = kb[i];
                if (a && (unsigned)(a >> 48) >= B16) { unsigned p = atomicAdd(&cntsh, 1u); Wl[p] = a; }
                if (b && (unsigned)(b >> 48) >= B16) { unsigned p = atomicAdd(&cntsh, 1u); Wl[p] = b; }
            }
            __syncthreads();
            const int n = (int)nExtsh;
            if (tid < n) {
                u64 my = Wl[tid];
                int r = 0;
                for (int j = 0; j < n; ++j) r += (Wl[j] > my) ? 1 : 0;
                if (r < CAND) {
                    unsigned c = 0xFFFFFFFFu - (unsigned)my;
                    float s = unordf((unsigned)(my >> 32));
                    float4 bb = ld_box(&cand_box[c]);
                    out[r * 5 + 0] = bb.x;
                    out[r * 5 + 1] = bb.y;
                    out[r * 5 + 2] = bb.z;
                    out[r * 5 + 3] = bb.w;
                    out[r * 5 + 4] = s;
                    out[500 + r]   = (float)(c / CAND);
                }
            }
            return;
        }

        // rare fallback: reload all keys, radix select from byte 5 (R9-proven)
        u64 keyv[32];
        #pragma unroll
        for (int j = 0; j < 32; ++j) {
            int idx = tid + 256 * j;
            keyv[j] = (idx < NC) ? ld_agent_u64(&cand_key[idx]) : 0ull;
        }
        if (tid == 0) Psh = (u64)B16 << 48;
        __syncthreads();

        const int plist[4] = {5, 4, 1, 0};   // bytes 3,2 always 0xFFFF: skip
        for (int pi = 0; pi < 4; ++pi) {
            if (donesh) break;
            const int p = plist[pi];
            const int shift = 8 * p;
            #pragma unroll
            for (int ww = 0; ww < 4; ++ww) hist[ww][tid] = 0;
            __syncthreads();

            u64 pfx = Psh;
            unsigned rem = remsh;
            u64 hmask = ~0ull << (shift + 8);
            #pragma unroll
            for (int j = 0; j < 32; ++j) {
                u64 kk = keyv[j];
                if (kk != 0ull && ((kk ^ pfx) & hmask) == 0ull)
                    atomicAdd(&hist[w][(unsigned)(kk >> shift) & 0xFFu], 1u);
            }
            __syncthreads();

            int b = 255 - tid;
            unsigned v = hist[0][b] + hist[1][b] + hist[2][b] + hist[3][b];
            unsigned inc = v;
            #pragma unroll
            for (int off = 1; off < 64; off <<= 1) {
                unsigned t2 = __shfl_up(inc, off);
                if (lane >= off) inc += t2;
            }
            if (lane == 63) wsum[w] = inc;
            __syncthreads();
            unsigned woff = 0;
            #pragma unroll
            for (int ww = 0; ww < 4; ++ww) if (ww < w) woff += wsum[ww];
            inc += woff;
            unsigned cumG = inc - v;
            if (v > 0 && rem >= cumG && rem < cumG + v) {
                u64 np = Psh | ((u64)(unsigned)b << shift);
                if (p == 4) np |= 0xFFFF0000ull;
                unsigned rem_new = rem - cumG;
                Psh = np;
                remsh = rem_new;
                donesh = (v == rem_new + 1) ? 1 : 0;
            }
            __syncthreads();
        }

        const u64 T = Psh;
        #pragma unroll
        for (int j = 0; j < 32; ++j) {
            u64 kk = keyv[j];
            if (kk >= T && kk != 0ull) {
                unsigned pos = atomicAdd(&cntsh, 1u);
                if (pos < 256) Wl[pos] = kk;
            }
        }
        __syncthreads();

        if (tid < CAND) {
            u64 my = Wl[tid];
            int r = 0;
            for (int j = 0; j < CAND; ++j) r += (Wl[j] > my) ? 1 : 0;
            unsigned c = 0xFFFFFFFFu - (unsigned)my;
            float s = unordf((unsigned)(my >> 32));
            float4 bb = ld_box(&cand_box[c]);
            out[r * 5 + 0] = bb.x;
            out[r * 5 + 1] = bb.y;
            out[r * 5 + 2] = bb.z;
            out[r * 5 + 3] = bb.w;
            out[r * 5 + 4] = s;
            out[500 + r]   = (float)(c / CAND);
        }
        return;
    }

    // ================= producer blocks (R9-proven P1/P2) =================
    const int k = blockIdx.x;
    const float Wf = (float)(*imw), Hf = (float)(*imh);

    // ---- P1: all score loads first (MLP), then ballots, box reg-prefetch
    float sv[4];
    #pragma unroll
    for (int t = 0; t < 4; ++t) {
        int i = w * 256 + t * 64 + lane;
        sv[t] = (i < R) ? scores[i * KP1 + k] : -1.f;
    }
    bool val[4]; unsigned posl[4];
    #pragma unroll
    for (int t = 0; t < 4; ++t) {
        bool v = sv[t] > SCORE_THRESH;
        u64 m = __ballot(v);
        val[t] = v;
        posl[t] = (unsigned)__popcll(m & ((1ull << lane) - 1ull));
        if (lane == 0) cnt16[w * 4 + t] = (unsigned)__popcll(m);
    }
    float4 rb[4];
    #pragma unroll
    for (int t = 0; t < 4; ++t) {
        if (val[t]) {
            int i = w * 256 + t * 64 + lane;
            rb[t] = *(const float4*)(boxes + (size_t)i * (K * 4) + (size_t)k * 4);
        }
    }
    __syncthreads();

    unsigned base4[4] = {0, 0, 0, 0};
    unsigned total = 0;
    #pragma unroll
    for (int x = 0; x < 16; ++x) {
        unsigned cc = cnt16[x];
        #pragma unroll
        for (int t = 0; t < 4; ++t) if (x < w * 4 + t) base4[t] += cc;
        total += cc;
    }
    const int V = total < VCAP ? (int)total : VCAP;

    #pragma unroll
    for (int t = 0; t < 4; ++t) {
        if (val[t]) {
            unsigned pos = base4[t] + posl[t];
            if (pos < VCAP) {
                skey[pos] = ((u64)ordf(sv[t]) << 32) | (u64)(0xFFFFFFFFu - pos);
                float4 bb = rb[t];
                bb.x = fminf(fmaxf(bb.x, 0.f), Wf);
                bb.y = fminf(fmaxf(bb.y, 0.f), Hf);
                bb.z = fminf(fmaxf(bb.z, 0.f), Wf);
                bb.w = fminf(fmaxf(bb.w, 0.f), Hf);
                sbox[pos] = bb;
            }
        }
    }
    __syncthreads();

    // ---- P2a: all-pairs rank-sort (distinct keys -> exact permutation)
    if (tid < V) {
        u64 my = skey[tid];
        int rank = 0;
        #pragma unroll 4
        for (int j = 0; j < V; ++j) rank += (skey[j] > my) ? 1 : 0;
        sboxs[rank] = sbox[tid];
        sscs[rank]  = unordf((unsigned)(my >> 32));
    }
    __syncthreads();

    // ---- P2b: ballot matrix (all waves)
    if (V > 0) {
        if (V <= 64)       build_matrix<1>(lane, w, V, sboxs, mat);
        else if (V <= 128) build_matrix<2>(lane, w, V, sboxs, mat);
        else               build_matrix<4>(lane, w, V, sboxs, mat);
    }
    __syncthreads();

    // ---- P2c: greedy scan + emit + signal (wave 0; no trailing barriers)
    if (w == 0) {
        if (V == 0) {
            for (int s2 = lane; s2 < CAND; s2 += 64)
                st_agent_u64(&cand_key[(size_t)k * CAND + s2], 0ull);
        } else if (V <= 64)  scan_emit<1>(k, lane, V, sboxs, sscs, mat, cand_key, cand_box);
        else if (V <= 128)   scan_emit<2>(k, lane, V, sboxs, sscs, mat, cand_key, cand_box);
        else                 scan_emit<4>(k, lane, V, sboxs, sscs, mat, cand_key, cand_box);

        // drain coherent stores, then signal this class done (monotone flag)
        asm volatile("s_waitcnt vmcnt(0)" ::: "memory");
        if (lane == 0)
            __hip_atomic_fetch_add(&g_flags[k], 1u, __ATOMIC_RELAXED, __HIP_MEMORY_SCOPE_AGENT);
    }
}

extern "C" void kernel_launch(void* const* d_in, const int* in_sizes, int n_in,
                              void* d_out, int out_size, void* d_ws, size_t ws_size,
                              hipStream_t stream) {
    const float* boxes  = (const float*)d_in[0];   // (1000, 320)
    const float* scores = (const float*)d_in[1];   // (1000, 81)
    const int*   imh    = (const int*)d_in[2];
    const int*   imw    = (const int*)d_in[3];
    float* out = (float*)d_out;

    u64*    cand_key = (u64*)d_ws;                       // 64000 B @ 0
    float4* cand_box = (float4*)((char*)d_ws + 65536);   // 128000 B @ 64 KiB

    fused_kernel<<<K + 1, 256, 0, stream>>>(boxes, scores, imh, imw,
                                            cand_key, cand_box, out);
}

// Round 11
// 22.439 us; speedup vs baseline: 1.3988x; 1.3988x over previous
//
#include <hip/hip_runtime.h>
#include <hip/hip_bf16.h>

#define R      1000
#define K      80
#define KP1    81
#define CAND   100
#define NC     (K*CAND)
#define VCAP   256
#define SCORE_THRESH 0.05f
#define NMS_THRESH   0.5f

typedef unsigned long long u64;

__device__ unsigned g_ctr = 0;   // module-load zero-init; each launch adds exactly K

__device__ __forceinline__ unsigned int ordf(float f) {
    unsigned int u = __float_as_uint(f);
    return (u & 0x80000000u) ? ~u : (u | 0x80000000u);
}
__device__ __forceinline__ float unordf(unsigned int o) {
    unsigned int u = (o & 0x80000000u) ? (o ^ 0x80000000u) : ~o;
    return __uint_as_float(u);
}

// Agent-scope coherent access (proven R7-R9)
__device__ __forceinline__ void st_agent_u64(u64* p, u64 v) {
    __hip_atomic_store(p, v, __ATOMIC_RELAXED, __HIP_MEMORY_SCOPE_AGENT);
}
__device__ __forceinline__ u64 ld_agent_u64(const u64* p) {
    return __hip_atomic_load(p, __ATOMIC_RELAXED, __HIP_MEMORY_SCOPE_AGENT);
}
__device__ __forceinline__ void st_box(float4* p, float4 b) {
    union { float f[2]; u64 u; } lo, hi;
    lo.f[0] = b.x; lo.f[1] = b.y; hi.f[0] = b.z; hi.f[1] = b.w;
    st_agent_u64((u64*)p, lo.u);
    st_agent_u64((u64*)p + 1, hi.u);
}
__device__ __forceinline__ float4 ld_box(const float4* p) {
    union { float f[2]; u64 u; } lo, hi;
    lo.u = ld_agent_u64((const u64*)p);
    hi.u = ld_agent_u64((const u64*)p + 1);
    return make_float4(lo.f[0], lo.f[1], hi.f[0], hi.f[1]);
}

// ---------------------------------------------------------------------------
// Ballot-matrix build (proven R6-R9)
// ---------------------------------------------------------------------------
template<int NR>
__device__ __forceinline__ void build_matrix(
    int lane, int w, int V, const float4* sboxs, u64* mat)
{
    float4 bx[NR]; float area[NR];
    #pragma unroll
    for (int r = 0; r < NR; ++r) {
        float4 bb = sboxs[r * 64 + lane];
        bx[r] = bb;
        area[r] = (bb.z - bb.x) * (bb.w - bb.y);
    }
    const int Vq = (V + 3) >> 2;
    int jbeg = w * Vq;
    int jend = jbeg + Vq; if (jend > V) jend = V;
    #pragma unroll 2
    for (int j = jbeg; j < jend; ++j) {
        float4 bj = sboxs[j];
        float areaB = (bj.z - bj.x) * (bj.w - bj.y);
        #pragma unroll
        for (int r = 0; r < NR; ++r) {
            float ltx = fmaxf(bx[r].x, bj.x), lty = fmaxf(bx[r].y, bj.y);
            float rbx = fminf(bx[r].z, bj.z), rby = fminf(bx[r].w, bj.w);
            float ww = fmaxf(rbx - ltx, 0.f), hh = fmaxf(rby - lty, 0.f);
            float inter = ww * hh;
            float uni = area[r] + areaB - inter;
            float iou = inter / fmaxf(uni, 1e-9f);   // bit-identical to ref
            mat[j * NR + r] = __ballot(iou > NMS_THRESH);
        }
    }
}

// ---------------------------------------------------------------------------
// Greedy scan (wave 0 only) + candidate emit (proven R6-R9)
// ---------------------------------------------------------------------------
template<int NR>
__device__ __forceinline__ void scan_emit(
    int k, int lane, int V,
    const float4* sboxs, const float* sscs, const u64* mat,
    u64* __restrict__ cand_key, float4* __restrict__ cand_box)
{
    const u64 lt_mask = (1ull << lane) - 1ull;

    u64 kept[NR];
    #pragma unroll
    for (int r = 0; r < NR; ++r) kept[r] = 0ull;
    u64 cur[NR];
    #pragma unroll
    for (int r = 0; r < NR; ++r) cur[r] = mat[r];

    int j = 0;
    #pragma unroll
    for (int jc = 0; jc < NR; ++jc) {
        int jmax = V - jc * 64;
        if (jmax > 64) jmax = 64;
        for (int jl = 0; jl < jmax; ++jl, ++j) {
            u64 nxt[NR];
            #pragma unroll
            for (int r = 0; r < NR; ++r) nxt[r] = mat[(j + 1) * NR + r];
            u64 hit = 0ull;
            #pragma unroll
            for (int r = 0; r < NR; ++r) hit |= cur[r] & kept[r];
            if (hit == 0ull) kept[jc] |= (1ull << jl);
            #pragma unroll
            for (int r = 0; r < NR; ++r) cur[r] = nxt[r];
        }
    }

    unsigned pre = 0;
    u64* ck = cand_key + (size_t)k * CAND;
    float4* cb = cand_box + (size_t)k * CAND;
    #pragma unroll
    for (int r = 0; r < NR; ++r) {
        u64 m = kept[r];
        bool mine = (m >> lane) & 1ull;
        unsigned rank = pre + (unsigned)__popcll(m & lt_mask);
        if (mine && rank < CAND) {
            unsigned c = (unsigned)(k * CAND + rank);
            float s = sscs[r * 64 + lane];
            st_agent_u64(&ck[rank], ((u64)ordf(s) << 32) | (u64)(0xFFFFFFFFu - c));
            st_box(&cb[rank], sboxs[r * 64 + lane]);
        }
        pre += (unsigned)__popcll(m);
    }
    unsigned T100 = pre < CAND ? pre : CAND;
    for (unsigned s2 = T100 + (unsigned)lane; s2 < CAND; s2 += 64)
        st_agent_u64(&ck[s2], 0ull);
}

// ---------------------------------------------------------------------------
// Single fused kernel: 80 blocks x 256 (R9, best proven: 22.2 us).
//  P1/P2: per-class gather->rank-sort->matrix->scan->emit
//  P3 (last block): ONE 768-bin histogram over 16-bit key prefix ->
//    threshold bin -> direct extraction + exact rank-select (common case);
//    radix fallback from byte 5 if threshold bin is huge.
// ---------------------------------------------------------------------------
__global__ __launch_bounds__(256, 1) void fused_kernel(
    const float* __restrict__ boxes, const float* __restrict__ scores,
    const int* __restrict__ imh, const int* __restrict__ imw,
    u64* __restrict__ cand_key, float4* __restrict__ cand_box,
    float* __restrict__ out)
{
    const int k = blockIdx.x, tid = threadIdx.x;
    const int lane = tid & 63, w = tid >> 6;

    __shared__ u64    skey[VCAP];
    __shared__ float4 sbox[VCAP];     // compacted order
    __shared__ float4 sboxs[VCAP];    // sorted order
    __shared__ float  sscs[VCAP];     // sorted scores
    __shared__ u64    mat[(VCAP + 1) * 4];
    __shared__ unsigned cnt16[16];
    __shared__ int lastf;
    __shared__ unsigned h768[768];
    __shared__ unsigned hist[4][264];
    __shared__ unsigned wsum[4];
    __shared__ u64 Psh;
    __shared__ unsigned remsh, cntsh, nExtsh, Bsh;
    __shared__ int donesh;
    __shared__ u64 Wl[256];

    const float Wf = (float)(*imw), Hf = (float)(*imh);

    // ---- P1: all score loads first (MLP), then ballots, box reg-prefetch
    float sv[4];
    #pragma unroll
    for (int t = 0; t < 4; ++t) {
        int i = w * 256 + t * 64 + lane;
        sv[t] = (i < R) ? scores[i * KP1 + k] : -1.f;
    }
    bool val[4]; unsigned posl[4];
    #pragma unroll
    for (int t = 0; t < 4; ++t) {
        bool v = sv[t] > SCORE_THRESH;
        u64 m = __ballot(v);
        val[t] = v;
        posl[t] = (unsigned)__popcll(m & ((1ull << lane) - 1ull));
        if (lane == 0) cnt16[w * 4 + t] = (unsigned)__popcll(m);
    }
    float4 rb[4];
    #pragma unroll
    for (int t = 0; t < 4; ++t) {
        if (val[t]) {
            int i = w * 256 + t * 64 + lane;
            rb[t] = *(const float4*)(boxes + (size_t)i * (K * 4) + (size_t)k * 4);
        }
    }
    __syncthreads();

    unsigned base4[4] = {0, 0, 0, 0};
    unsigned total = 0;
    #pragma unroll
    for (int x = 0; x < 16; ++x) {
        unsigned cc = cnt16[x];
        #pragma unroll
        for (int t = 0; t < 4; ++t) if (x < w * 4 + t) base4[t] += cc;
        total += cc;
    }
    const int V = total < VCAP ? (int)total : VCAP;

    #pragma unroll
    for (int t = 0; t < 4; ++t) {
        if (val[t]) {
            unsigned pos = base4[t] + posl[t];
            if (pos < VCAP) {
                skey[pos] = ((u64)ordf(sv[t]) << 32) | (u64)(0xFFFFFFFFu - pos);
                float4 bb = rb[t];
                bb.x = fminf(fmaxf(bb.x, 0.f), Wf);
                bb.y = fminf(fmaxf(bb.y, 0.f), Hf);
                bb.z = fminf(fmaxf(bb.z, 0.f), Wf);
                bb.w = fminf(fmaxf(bb.w, 0.f), Hf);
                sbox[pos] = bb;
            }
        }
    }
    __syncthreads();

    // ---- P2a: all-pairs rank-sort (distinct keys -> exact permutation)
    if (tid < V) {
        u64 my = skey[tid];
        int rank = 0;
        #pragma unroll 4
        for (int j = 0; j < V; ++j) rank += (skey[j] > my) ? 1 : 0;
        sboxs[rank] = sbox[tid];
        sscs[rank]  = unordf((unsigned)(my >> 32));
    }
    __syncthreads();

    // ---- P2b: ballot matrix (all waves)
    if (V > 0) {
        if (V <= 64)       build_matrix<1>(lane, w, V, sboxs, mat);
        else if (V <= 128) build_matrix<2>(lane, w, V, sboxs, mat);
        else               build_matrix<4>(lane, w, V, sboxs, mat);
    }
    __syncthreads();

    // ---- P2c: greedy scan + emit (wave 0)
    if (w == 0) {
        if (V == 0) {
            for (int s2 = lane; s2 < CAND; s2 += 64)
                st_agent_u64(&cand_key[(size_t)k * CAND + s2], 0ull);
        } else if (V <= 64)  scan_emit<1>(k, lane, V, sboxs, sscs, mat, cand_key, cand_box);
        else if (V <= 128)   scan_emit<2>(k, lane, V, sboxs, sscs, mat, cand_key, cand_box);
        else                 scan_emit<4>(k, lane, V, sboxs, sscs, mat, cand_key, cand_box);
    }
    __syncthreads();   // coherent stores drained before handshake

    // ---- handshake (proven R6-R9)
    if (tid == 0) {
        unsigned old = __hip_atomic_fetch_add(&g_ctr, 1u, __ATOMIC_RELAXED, __HIP_MEMORY_SCOPE_AGENT);
        lastf = ((old % (unsigned)K) == (unsigned)(K - 1)) ? 1 : 0;
    }
    __syncthreads();
    if (!lastf) return;

    // ---- P3: exact top-100 of 8000 distinct keys
    u64 keyv[32];
    #pragma unroll
    for (int j = 0; j < 32; ++j) {
        int idx = tid + 256 * j;
        keyv[j] = (idx < NC) ? ld_agent_u64(&cand_key[idx]) : 0ull;
    }

    // one-pass 768-bin histogram over bits 63..48; byte7 in {0xBD,0xBE,0xBF}
    #pragma unroll
    for (int x = 0; x < 3; ++x) h768[x * 256 + tid] = 0;
    __syncthreads();
    #pragma unroll
    for (int j = 0; j < 32; ++j) {
        u64 kk = keyv[j];
        if (kk != 0ull)
            atomicAdd(&h768[(unsigned)(kk >> 48) - 0xBD00u], 1u);
    }
    __syncthreads();

    // suffix-scan (bin-descending) to locate the rank-99 threshold bin
    {
        unsigned h0 = h768[3 * tid], h1 = h768[3 * tid + 1], h2 = h768[3 * tid + 2];
        unsigned local = h0 + h1 + h2;
        unsigned inc = local;   // inclusive suffix over lanes (lane l: sum l..63)
        #pragma unroll
        for (int off = 1; off < 64; off <<= 1) {
            unsigned v = __shfl_down(inc, off);
            if (lane + off < 64) inc += v;
        }
        if (lane == 0) wsum[w] = inc;   // wave total
        __syncthreads();
        unsigned wafter = 0;
        #pragma unroll
        for (int ww = 0; ww < 4; ++ww) if (ww > w) wafter += wsum[ww];
        unsigned after = inc - local + wafter;   // keys in bins > 3*tid+2

        unsigned G2 = after;
        unsigned G1 = after + h2;
        unsigned G0 = after + h2 + h1;
        if (h2 && G2 <= CAND - 1 && CAND - 1 < G2 + h2) {
            Bsh = 3 * tid + 2; remsh = CAND - 1 - G2; nExtsh = G2 + h2; cntsh = 0; donesh = 0;
        }
        if (h1 && G1 <= CAND - 1 && CAND - 1 < G1 + h1) {
            Bsh = 3 * tid + 1; remsh = CAND - 1 - G1; nExtsh = G1 + h1; cntsh = 0; donesh = 0;
        }
        if (h0 && G0 <= CAND - 1 && CAND - 1 < G0 + h0) {
            Bsh = 3 * tid;     remsh = CAND - 1 - G0; nExtsh = G0 + h0; cntsh = 0; donesh = 0;
        }
        __syncthreads();
    }

    const unsigned B16 = Bsh + 0xBD00u;

    if (nExtsh <= 256) {
        // ---- common case: extract all keys >= bin floor, exact rank-select
        #pragma unroll
        for (int j = 0; j < 32; ++j) {
            u64 kk = keyv[j];
            if (kk != 0ull && (unsigned)(kk >> 48) >= B16) {
                unsigned pos = atomicAdd(&cntsh, 1u);
                Wl[pos] = kk;
            }
        }
        __syncthreads();
        const int n = (int)nExtsh;
        if (tid < n) {
            u64 my = Wl[tid];
            int r = 0;
            for (int j = 0; j < n; ++j) r += (Wl[j] > my) ? 1 : 0;
            if (r < CAND) {
                unsigned c = 0xFFFFFFFFu - (unsigned)my;
                float s = unordf((unsigned)(my >> 32));
                float4 bb = ld_box(&cand_box[c]);
                out[r * 5 + 0] = bb.x;
                out[r * 5 + 1] = bb.y;
                out[r * 5 + 2] = bb.z;
                out[r * 5 + 3] = bb.w;
                out[r * 5 + 4] = s;
                out[500 + r]   = (float)(c / CAND);
            }
        }
        return;
    }

    // ---- rare fallback: radix select continuing at byte 5 (prefix = B16)
    if (tid == 0) Psh = (u64)B16 << 48;
    __syncthreads();

    const int plist[4] = {5, 4, 1, 0};   // bytes 3,2 always 0xFFFF: skip
    for (int pi = 0; pi < 4; ++pi) {
        if (donesh) break;
        const int p = plist[pi];
        const int shift = 8 * p;
        #pragma unroll
        for (int ww = 0; ww < 4; ++ww) hist[ww][tid] = 0;
        __syncthreads();

        u64 pfx = Psh;
        unsigned rem = remsh;
        u64 hmask = ~0ull << (shift + 8);
        #pragma unroll
        for (int j = 0; j < 32; ++j) {
            u64 kk = keyv[j];
            if (kk != 0ull && ((kk ^ pfx) & hmask) == 0ull)
                atomicAdd(&hist[w][(unsigned)(kk >> shift) & 0xFFu], 1u);
        }
        __syncthreads();

        int b = 255 - tid;
        unsigned v = hist[0][b] + hist[1][b] + hist[2][b] + hist[3][b];
        unsigned inc = v;
        #pragma unroll
        for (int off = 1; off < 64; off <<= 1) {
            unsigned t2 = __shfl_up(inc, off);
            if (lane >= off) inc += t2;
        }
        if (lane == 63) wsum[w] = inc;
        __syncthreads();
        unsigned woff = 0;
        #pragma unroll
        for (int ww = 0; ww < 4; ++ww) if (ww < w) woff += wsum[ww];
        inc += woff;
        unsigned cumG = inc - v;
        if (v > 0 && rem >= cumG && rem < cumG + v) {
            u64 np = Psh | ((u64)(unsigned)b << shift);
            if (p == 4) np |= 0xFFFF0000ull;
            unsigned rem_new = rem - cumG;
            Psh = np;
            remsh = rem_new;
            donesh = (v == rem_new + 1) ? 1 : 0;
        }
        __syncthreads();
    }

    const u64 T = Psh;   // exact rank-99 threshold (full or zero-extended)
    #pragma unroll
    for (int j = 0; j < 32; ++j) {
        u64 kk = keyv[j];
        if (kk >= T && kk != 0ull) {
            unsigned pos = atomicAdd(&cntsh, 1u);
            if (pos < 256) Wl[pos] = kk;
        }
    }
    __syncthreads();

    if (tid < CAND) {
        u64 my = Wl[tid];
        int r = 0;
        for (int j = 0; j < CAND; ++j) r += (Wl[j] > my) ? 1 : 0;
        unsigned c = 0xFFFFFFFFu - (unsigned)my;
        float s = unordf((unsigned)(my >> 32));
        float4 bb = ld_box(&cand_box[c]);
        out[r * 5 + 0] = bb.x;
        out[r * 5 + 1] = bb.y;
        out[r * 5 + 2] = bb.z;
        out[r * 5 + 3] = bb.w;
        out[r * 5 + 4] = s;
        out[500 + r]   = (float)(c / CAND);
    }
}

extern "C" void kernel_launch(void* const* d_in, const int* in_sizes, int n_in,
                              void* d_out, int out_size, void* d_ws, size_t ws_size,
                              hipStream_t stream) {
    const float* boxes  = (const float*)d_in[0];   // (1000, 320)
    const float* scores = (const float*)d_in[1];   // (1000, 81)
    const int*   imh    = (const int*)d_in[2];
    const int*   imw    = (const int*)d_in[3];
    float* out = (float*)d_out;

    u64*    cand_key = (u64*)d_ws;                       // 64000 B @ 0
    float4* cand_box = (float4*)((char*)d_ws + 65536);   // 128000 B @ 64 KiB

    fused_kernel<<<K, 256, 0, stream>>>(boxes, scores, imh, imw,
                                        cand_key, cand_box, out);
}